// Round 1
// baseline (270.706 us; speedup 1.0000x reference)
//
#include <hip/hip_runtime.h>

// Segment-normalized chunked linear:
//   y = x @ W.T            (x: [N,4] fp32, W: [4,4] fp32)
//   seg(i) = largest s with slices[s] <= i   (slices: [4097] int32, monotone)
//   seg_abs[s] = sum over rows in segment s of sum_j |y[i,j]|
//   out = y / seg_abs[seg(i)]
//
// Pass 1: stream x, accumulate per-segment |y| sums (LDS hist -> global atomics).
// Pass 2: stream x again (LLC-warm), recompute y, normalize, write out.
// Memory-bound: ~270-400 MB HBM traffic total.

#define NSEG 4096
#define BLK 256
#define RPT 16                 // rows per thread
#define CHUNK (BLK * RPT)      // 4096 rows per block

__global__ __launch_bounds__(BLK) void seg_pass1(
    const float4* __restrict__ x, const int* __restrict__ slices,
    const float* __restrict__ W, float* __restrict__ seg_abs, int n)
{
    __shared__ int   sl[NSEG + 1];
    __shared__ float hist[NSEG];
    for (int i = threadIdx.x; i < NSEG + 1; i += BLK) sl[i] = slices[i];
    for (int i = threadIdx.x; i < NSEG; i += BLK) hist[i] = 0.0f;

    float w[16];
#pragma unroll
    for (int i = 0; i < 16; ++i) w[i] = W[i];
    __syncthreads();

    int base = blockIdx.x * CHUNK + threadIdx.x;

    // initial segment: upper_bound(base) - 1 via binary search in LDS
    int lo = 0, hi = NSEG;
    {
        int r0 = (base < n) ? base : (n - 1);
        while (hi - lo > 1) { int mid = (lo + hi) >> 1; if (sl[mid] <= r0) lo = mid; else hi = mid; }
    }
    int seg = lo;
    float acc = 0.0f;

#pragma unroll
    for (int it = 0; it < RPT; ++it) {
        int r = base + it * BLK;
        if (r < n) {
            // amortized walk: rows advance by BLK, segments avg 2048 rows
            int s = seg;
            while (s < NSEG - 1 && sl[s + 1] <= r) ++s;
            float4 v = x[r];
            float y0 = fabsf(v.x * w[0]  + v.y * w[1]  + v.z * w[2]  + v.w * w[3]);
            float y1 = fabsf(v.x * w[4]  + v.y * w[5]  + v.z * w[6]  + v.w * w[7]);
            float y2 = fabsf(v.x * w[8]  + v.y * w[9]  + v.z * w[10] + v.w * w[11]);
            float y3 = fabsf(v.x * w[12] + v.y * w[13] + v.z * w[14] + v.w * w[15]);
            float a = (y0 + y1) + (y2 + y3);
            if (s != seg) { atomicAdd(&hist[seg], acc); acc = 0.0f; seg = s; }
            acc += a;
        }
    }
    if (acc != 0.0f) atomicAdd(&hist[seg], acc);
    __syncthreads();

    // flush block-local histogram; ~2-3 nonzero bins per block on average
    for (int i = threadIdx.x; i < NSEG; i += BLK) {
        float h = hist[i];
        if (h != 0.0f) atomicAdd(&seg_abs[i], h);
    }
}

__global__ __launch_bounds__(BLK) void seg_pass2(
    const float4* __restrict__ x, const int* __restrict__ slices,
    const float* __restrict__ W, const float* __restrict__ seg_abs,
    float4* __restrict__ out, int n)
{
    __shared__ int sl[NSEG + 1];
    for (int i = threadIdx.x; i < NSEG + 1; i += BLK) sl[i] = slices[i];

    float w[16];
#pragma unroll
    for (int i = 0; i < 16; ++i) w[i] = W[i];
    __syncthreads();

    int base = blockIdx.x * CHUNK + threadIdx.x;

    int lo = 0, hi = NSEG;
    {
        int r0 = (base < n) ? base : (n - 1);
        while (hi - lo > 1) { int mid = (lo + hi) >> 1; if (sl[mid] <= r0) lo = mid; else hi = mid; }
    }
    int seg = lo;
    float inv = 1.0f / seg_abs[seg];   // seg_abs hot in L2; wave-uniform -> broadcast

#pragma unroll
    for (int it = 0; it < RPT; ++it) {
        int r = base + it * BLK;
        if (r < n) {
            int s = seg;
            while (s < NSEG - 1 && sl[s + 1] <= r) ++s;
            if (s != seg) { seg = s; inv = 1.0f / seg_abs[seg]; }
            float4 v = x[r];
            float4 o;
            o.x = (v.x * w[0]  + v.y * w[1]  + v.z * w[2]  + v.w * w[3])  * inv;
            o.y = (v.x * w[4]  + v.y * w[5]  + v.z * w[6]  + v.w * w[7])  * inv;
            o.z = (v.x * w[8]  + v.y * w[9]  + v.z * w[10] + v.w * w[11]) * inv;
            o.w = (v.x * w[12] + v.y * w[13] + v.z * w[14] + v.w * w[15]) * inv;
            out[r] = o;
        }
    }
}

extern "C" void kernel_launch(void* const* d_in, const int* in_sizes, int n_in,
                              void* d_out, int out_size, void* d_ws, size_t ws_size,
                              hipStream_t stream) {
    const float4* x      = (const float4*)d_in[0];
    const int*    slices = (const int*)d_in[1];
    const float*  W      = (const float*)d_in[2];
    float*        seg_abs = (float*)d_ws;      // NSEG floats of scratch
    float4*       out    = (float4*)d_out;
    int n = in_sizes[0] / 4;                   // number of rows

    hipMemsetAsync(d_ws, 0, NSEG * sizeof(float), stream);  // ws is poisoned 0xAA

    int nblocks = (n + CHUNK - 1) / CHUNK;
    seg_pass1<<<nblocks, BLK, 0, stream>>>(x, slices, W, seg_abs, n);
    seg_pass2<<<nblocks, BLK, 0, stream>>>(x, slices, W, seg_abs, out, n);
}

// Round 2
// 266.935 us; speedup vs baseline: 1.0141x; 1.0141x over previous
//
#include <hip/hip_runtime.h>

// Segment-normalized chunked linear:
//   y = x @ W.T            (x: [N,4] fp32, W: [4,4] fp32)
//   seg(i) = largest s with slices[s] <= i   (slices: [4097] int32, monotone)
//   seg_abs[s] = sum over rows in segment s of sum_j |y[i,j]|
//   out = y / seg_abs[seg(i)]
//
// Pass 1: stream x, accumulate per-segment |y| sums (LDS hist -> global atomics).
// Pass 2: stream x again (should be LLC-resident), recompute y, normalize,
//         nontemporal-store out so the write stream doesn't evict x from L3.
// HBM floor: ~268 MB -> ~45 us; everything else is overhead to grind down.

#define NSEG  4096
#define BLK   256
#define RPT   16                  // rows per thread
#define BATCH 8                   // loads issued back-to-back (MLP)
#define CHUNK (BLK * RPT)         // 4096 rows per block

typedef float v4 __attribute__((ext_vector_type(4)));

__device__ __forceinline__ float absrow(v4 v, const float* w) {
    float y0 = fabsf(v.x * w[0]  + v.y * w[1]  + v.z * w[2]  + v.w * w[3]);
    float y1 = fabsf(v.x * w[4]  + v.y * w[5]  + v.z * w[6]  + v.w * w[7]);
    float y2 = fabsf(v.x * w[8]  + v.y * w[9]  + v.z * w[10] + v.w * w[11]);
    float y3 = fabsf(v.x * w[12] + v.y * w[13] + v.z * w[14] + v.w * w[15]);
    return (y0 + y1) + (y2 + y3);
}

__global__ __launch_bounds__(BLK) void seg_pass1(
    const v4* __restrict__ x, const int* __restrict__ slices,
    const float* __restrict__ W, float* __restrict__ seg_abs, int n)
{
    __shared__ int   sl[NSEG + 1];
    __shared__ float hist[NSEG];
#pragma unroll
    for (int i = threadIdx.x; i < NSEG + 1; i += BLK) sl[i] = slices[i];
#pragma unroll
    for (int i = threadIdx.x; i < NSEG; i += BLK) hist[i] = 0.0f;

    float w[16];
#pragma unroll
    for (int i = 0; i < 16; ++i) w[i] = W[i];
    __syncthreads();

    const int base = blockIdx.x * CHUNK + threadIdx.x;

    // initial segment: upper_bound(base) - 1 via binary search in LDS
    int lo = 0, hi = NSEG;
    {
        int r0 = (base < n) ? base : (n - 1);
        while (hi - lo > 1) { int mid = (lo + hi) >> 1; if (sl[mid] <= r0) lo = mid; else hi = mid; }
    }
    int seg = lo;
    float acc = 0.0f;

    const bool full = (base + (RPT - 1) * BLK) < n;   // true for every block here
    if (full) {
#pragma unroll
        for (int b = 0; b < RPT / BATCH; ++b) {
            v4 d[BATCH];
#pragma unroll
            for (int j = 0; j < BATCH; ++j)           // 8 loads issue back-to-back
                d[j] = x[base + (b * BATCH + j) * BLK];
#pragma unroll
            for (int j = 0; j < BATCH; ++j) {
                int r = base + (b * BATCH + j) * BLK;
                int s = seg;
                while (s < NSEG - 1 && sl[s + 1] <= r) ++s;
                if (s != seg) { atomicAdd(&hist[seg], acc); acc = 0.0f; seg = s; }
                acc += absrow(d[j], w);
            }
        }
    } else {
        for (int it = 0; it < RPT; ++it) {
            int r = base + it * BLK;
            if (r < n) {
                int s = seg;
                while (s < NSEG - 1 && sl[s + 1] <= r) ++s;
                if (s != seg) { atomicAdd(&hist[seg], acc); acc = 0.0f; seg = s; }
                acc += absrow(x[r], w);
            }
        }
    }
    if (acc != 0.0f) atomicAdd(&hist[seg], acc);
    __syncthreads();

    // flush block-local histogram; ~2-3 nonzero bins per block on average
#pragma unroll
    for (int i = threadIdx.x; i < NSEG; i += BLK) {
        float h = hist[i];
        if (h != 0.0f) atomicAdd(&seg_abs[i], h);
    }
}

__global__ __launch_bounds__(BLK) void seg_pass2(
    const v4* __restrict__ x, const int* __restrict__ slices,
    const float* __restrict__ W, const float* __restrict__ seg_abs,
    v4* __restrict__ out, int n)
{
    __shared__ int sl[NSEG + 1];
#pragma unroll
    for (int i = threadIdx.x; i < NSEG + 1; i += BLK) sl[i] = slices[i];

    float w[16];
#pragma unroll
    for (int i = 0; i < 16; ++i) w[i] = W[i];
    __syncthreads();

    const int base = blockIdx.x * CHUNK + threadIdx.x;

    int lo = 0, hi = NSEG;
    {
        int r0 = (base < n) ? base : (n - 1);
        while (hi - lo > 1) { int mid = (lo + hi) >> 1; if (sl[mid] <= r0) lo = mid; else hi = mid; }
    }
    int seg = lo;
    float inv = 1.0f / seg_abs[seg];

    const bool full = (base + (RPT - 1) * BLK) < n;
    if (full) {
#pragma unroll
        for (int b = 0; b < RPT / BATCH; ++b) {
            v4 d[BATCH];
#pragma unroll
            for (int j = 0; j < BATCH; ++j)
                d[j] = x[base + (b * BATCH + j) * BLK];
#pragma unroll
            for (int j = 0; j < BATCH; ++j) {
                int r = base + (b * BATCH + j) * BLK;
                int s = seg;
                while (s < NSEG - 1 && sl[s + 1] <= r) ++s;
                if (s != seg) { seg = s; inv = 1.0f / seg_abs[seg]; }
                v4 v = d[j], o;
                o.x = (v.x * w[0]  + v.y * w[1]  + v.z * w[2]  + v.w * w[3])  * inv;
                o.y = (v.x * w[4]  + v.y * w[5]  + v.z * w[6]  + v.w * w[7])  * inv;
                o.z = (v.x * w[8]  + v.y * w[9]  + v.z * w[10] + v.w * w[11]) * inv;
                o.w = (v.x * w[12] + v.y * w[13] + v.z * w[14] + v.w * w[15]) * inv;
                __builtin_nontemporal_store(o, &out[r]);   // keep x resident in L3
            }
        }
    } else {
        for (int it = 0; it < RPT; ++it) {
            int r = base + it * BLK;
            if (r < n) {
                int s = seg;
                while (s < NSEG - 1 && sl[s + 1] <= r) ++s;
                if (s != seg) { seg = s; inv = 1.0f / seg_abs[seg]; }
                v4 v = x[r], o;
                o.x = (v.x * w[0]  + v.y * w[1]  + v.z * w[2]  + v.w * w[3])  * inv;
                o.y = (v.x * w[4]  + v.y * w[5]  + v.z * w[6]  + v.w * w[7])  * inv;
                o.z = (v.x * w[8]  + v.y * w[9]  + v.z * w[10] + v.w * w[11]) * inv;
                o.w = (v.x * w[12] + v.y * w[13] + v.z * w[14] + v.w * w[15]) * inv;
                __builtin_nontemporal_store(o, &out[r]);
            }
        }
    }
}

extern "C" void kernel_launch(void* const* d_in, const int* in_sizes, int n_in,
                              void* d_out, int out_size, void* d_ws, size_t ws_size,
                              hipStream_t stream) {
    const v4*   x      = (const v4*)d_in[0];
    const int*  slices = (const int*)d_in[1];
    const float* W     = (const float*)d_in[2];
    float*      seg_abs = (float*)d_ws;       // NSEG floats of scratch
    v4*         out    = (v4*)d_out;
    int n = in_sizes[0] / 4;                  // number of rows

    hipMemsetAsync(d_ws, 0, NSEG * sizeof(float), stream);  // ws is poisoned 0xAA

    int nblocks = (n + CHUNK - 1) / CHUNK;
    seg_pass1<<<nblocks, BLK, 0, stream>>>(x, slices, W, seg_abs, n);
    seg_pass2<<<nblocks, BLK, 0, stream>>>(x, slices, W, seg_abs, out, n);
}